// Round 5
// baseline (3776.657 us; speedup 1.0000x reference)
//
#include <hip/hip_runtime.h>

#define N_B   64
#define N_T   1000
#define N_IN  80
#define N_REC 512
#define N_OUT 20
#define THR 1.0f

constexpr float ALPHA = 0.9512294245007140f; // exp(-1/20)
constexpr float KAPPA = 0.9512294245007140f;

typedef short bf16x8 __attribute__((ext_vector_type(8)));
typedef float f32x4  __attribute__((ext_vector_type(4)));

// lgkm-only barrier: LDS visibility without draining global loads/stores/atomics.
__device__ __forceinline__ void barrier_lgkm() {
    asm volatile("s_waitcnt lgkmcnt(0)" ::: "memory");
    __builtin_amdgcn_s_barrier();
}

__device__ __forceinline__ unsigned short f2bf(float f) {   // RNE fp32->bf16
    unsigned u = __builtin_bit_cast(unsigned, f);
    return (unsigned short)((u + 0x7FFFu + ((u >> 16) & 1u)) >> 16);
}
__device__ __forceinline__ float bf2f(unsigned short h) {
    return __builtin_bit_cast(float, (unsigned)h << 16);
}

// ---------------------------------------------------------------------------
// Kernel P: pack w_rec (diag zeroed) into MFMA B-fragments, 3-way bf16 split
// (hi+mid+lo, residual <= 2^-27 relative -- below fp32 ulp, so the GEMM is
// numerically "another fp32 order"). K-slot mapping kappa(lane,i) =
// 16*(i>>2) + 4*(lane>>4) + (i&3) is applied to BOTH A (spikes, built in
// k_scan) and B (here), so any HW K-permutation cancels exactly.
// Frag addressing: gid = ((((ns*2+kh)*4+nt)*8+ksl)*3+s)*64 + lane.
// Also zeroes the mask-exchange area (stamps must be < t0 at launch).
// ---------------------------------------------------------------------------
__global__ void k_prep(const float* __restrict__ w_rec, unsigned* __restrict__ wPack,
                       unsigned long long* __restrict__ ex) {
    int gid = blockIdx.x * 256 + threadIdx.x;     // 0 .. 98303
    if (gid < 32 * 2 * 32) ex[gid] = 0ull;        // 2048 exchange slots
    if (gid >= 8 * 2 * 4 * 8 * 3 * 64) return;
    int lane = gid & 63;
    int fg   = gid >> 6;
    int s    = fg % 3;
    int q    = fg / 3;
    int ksl  = q & 7;
    int nt   = (q >> 3) & 3;
    int kh   = (q >> 5) & 1;
    int ns   = q >> 6;
    int n  = ns * 64 + nt * 16 + (lane & 15);
    int kb = (kh * 8 + ksl) * 32 + 4 * (lane >> 4);
    unsigned u[4];
#pragma unroll
    for (int j = 0; j < 4; ++j) {
        unsigned short h2v[2];
#pragma unroll
        for (int e = 0; e < 2; ++e) {
            int i = j * 2 + e;
            int k = kb + ((i >> 2) << 4) + (i & 3);
            float w0 = (k == n) ? 0.0f : w_rec[(size_t)n * N_REC + k];
            unsigned short h1 = f2bf(w0);
            float r1 = w0 - bf2f(h1);
            unsigned short hm = f2bf(r1);
            float r2 = r1 - bf2f(hm);
            unsigned short hl = f2bf(r2);
            h2v[e] = (s == 0) ? h1 : (s == 1) ? hm : hl;
        }
        u[j] = (unsigned)h2v[0] | ((unsigned)h2v[1] << 16);
    }
    ((uint4*)wPack)[gid] = make_uint4(u[0], u[1], u[2], u[3]);
}

// ---------------------------------------------------------------------------
// Kernel B: inj[(t-t0)*64 + b][r] = dot(x[b,t-1,:], w_in[r,:]) (masked) + noise[t,b,r]
// ---------------------------------------------------------------------------
__global__ __launch_bounds__(512, 2) void k_inj(
    const float* __restrict__ x, const float* __restrict__ w_in,
    const float* __restrict__ noise, const int* __restrict__ seq,
    float* __restrict__ inj, int t0, int t1)
{
    const int r = threadIdx.x;
    float wreg[N_IN];
#pragma unroll
    for (int i = 0; i < N_IN; ++i) wreg[i] = w_in[r * N_IN + i];

    const int P = (t1 - t0) * N_B;
    const int stride = gridDim.x;

    auto nz = [&](int p) -> float {
        int pt = p >> 6, b = p & 63, t = t0 + pt;
        return __builtin_nontemporal_load(noise + ((size_t)t * N_B + b) * N_REC + r);
    };

    int p = blockIdx.x;
    float nxt = (p < P) ? nz(p) : 0.0f;
    for (; p < P; p += stride) {
        float acc = nxt;
        if (p + stride < P) nxt = nz(p + stride);
        int pt = p >> 6;
        int b  = p & 63;
        int t  = t0 + pt;
        if (t - 1 < seq[b]) {
            const float* xr = x + ((size_t)b * N_T + (t - 1)) * N_IN;
#pragma unroll
            for (int i = 0; i < N_IN; ++i) acc = fmaf(wreg[i], xr[i], acc);
        }
        inj[(size_t)p * N_REC + r] = acc;
    }
}

// ---------------------------------------------------------------------------
// Kernel C: sequential scan via dense MFMA. Grid = 32 = 4 batch-groups (bg,
// 16 batches) x 8 neuron-slices (ns, 64 neurons). Per step, per block:
//   P1: write own z(t-1) ballots to LDS; poll the 7 partner slices' stamped
//       ballots (self-validating (t<<32)|mask32 atomicExch words, depth-2
//       parity ring -- protocol proven in rounds 3/4, causality arg holds
//       all-to-all: my publish(t) follows my poll(t-1) success, which follows
//       every partner's publish(t-1), which follows their consume(t-2)).
//   P2: build Z (16x512 bf16 {0,1}) in LDS from the 8 slices' ballots.
//   P3: GEMM acc = Z @ W_slice^T on matrix cores. W in VGPRs (96/wave,
//       loaded once): 8 waves = 4 N-tiles x 2 K-halves, 8 K-steps x 3 splits
//       = 24 mfma_16x16x32_bf16 per wave per step. Zero per-step W traffic.
//   P4: waves 0-3: K-half reduce (LDS), membrane update in C-layout
//       (row=(lane>>4)*4+reg=batch, col=lane&15=neuron), ballot, publish.
//       waves 4-7: vo partial over own 64 neurons from z(t-1) bitmask ->
//       vop buffer (summed into out_vo by k_vored).
// All in-loop barriers are lgkm-only; inj prefetch/publish/vop stores stay
// in flight across them.
// ---------------------------------------------------------------------------
__global__ __launch_bounds__(512, 1) void k_scan(
    const unsigned* __restrict__ wPack, const float* __restrict__ inj,
    const float* __restrict__ w_out, float* __restrict__ vop,
    int t0, int t1,
    float* __restrict__ st_v, unsigned long long* __restrict__ st_bal,
    float* __restrict__ st_vop, unsigned long long* __restrict__ ex)
{
    const int bid  = blockIdx.x;
    const int bg   = bid >> 3;
    const int ns   = bid & 7;
    const int tid  = threadIdx.x;
    const int wv   = tid >> 6;
    const int lane = tid & 63;
    const int nt   = wv & 3;
    const int kh   = wv >> 2;

    __shared__ uint4 zlds[64 * 16];                // [kl=ks*4+lgrp][m], bf16x8 frags
    __shared__ unsigned bal32[8][4][4][2];         // [ns][wave][r][half]
    __shared__ f32x4 red[4][64];                   // K-half partials
    __shared__ alignas(16) float wo[20][68];       // w_out slice, +4 pad (bank-free)

    // W fragments -> VGPRs (once)
    bf16x8 wreg[24];
    {
        const uint4* wp = (const uint4*)wPack + (size_t)(((ns * 2 + kh) * 4 + nt) * 24) * 64;
#pragma unroll
        for (int j = 0; j < 24; ++j)
            wreg[j] = __builtin_bit_cast(bf16x8, wp[j * 64 + lane]);
    }
    for (int idx = tid; idx < 20 * 64; idx += 512)
        wo[idx >> 6][idx & 63] = w_out[(size_t)(idx >> 6) * N_REC + ns * 64 + (idx & 63)];

    float v0 = 0, v1 = 0, v2 = 0, v3 = 0;
    int zprev = 0;
    unsigned long long bm0 = 0, bm1 = 0, bm2 = 0, bm3 = 0;
    float vo0 = 0, vo1 = 0;

    if (t0 == 1) {
        if (tid < 256) (&bal32[0][0][0][0])[tid] = 0u;
    } else {
        if (tid < 256) {
            unsigned long long wd = st_bal[bg * 128 + (tid >> 1)];
            (&bal32[0][0][0][0])[tid] = (unsigned)(wd >> (32 * (tid & 1)));
        }
        if (wv < 4) {
            f32x4 sv = ((const f32x4*)st_v)[bid * 256 + tid];
            v0 = sv[0]; v1 = sv[1]; v2 = sv[2]; v3 = sv[3];
        } else {
            int q = tid - 256;
            vo0 = st_vop[bid * 320 + q];
            if (q < 64) vo1 = st_vop[bid * 320 + 256 + q];
        }
    }
    __syncthreads();
    if (wv < 4) {   // zprev bits from own slice ballots
        int h = lane >> 5, sh = lane & 31;
#pragma unroll
        for (int r = 0; r < 4; ++r)
            zprev |= (int)((bal32[ns][wv][r][h] >> sh) & 1u) << r;
    }

    auto bmsel = [&](int r) -> unsigned long long {
        return (r == 0) ? bm0 : (r == 1) ? bm1 : (r == 2) ? bm2 : bm3;
    };
    auto injaddr = [&](int trel, int r) -> const float* {
        return inj + ((size_t)trel * 64 + bg * 16 + (lane >> 4) * 4 + r) * N_REC
                   + ns * 64 + nt * 16 + (lane & 15);
    };
    // vo partial over own 64 neurons from z bitmask (reads bal32[ns])
    auto vo_step = [&](int slot) {
        int q = tid - 256;
        int m = q & 15, o = q >> 4;
        unsigned long long mask = 0;
#pragma unroll
        for (int w2 = 0; w2 < 4; ++w2) {
            unsigned long long wd = (unsigned long long)bal32[ns][w2][m & 3][0]
                                  | ((unsigned long long)bal32[ns][w2][m & 3][1] << 32);
            mask |= ((wd >> ((m >> 2) * 16)) & 0xFFFFull) << (16 * w2);
        }
        float s0 = 0.f, s1 = 0.f;
#pragma unroll
        for (int jj = 0; jj < 16; ++jj) {
            unsigned nib = (unsigned)(mask >> (4 * jj)) & 0xFu;
            float4 wa = *(const float4*)&wo[o][jj * 4];
            s0 += (nib & 1u) ? wa.x : 0.f;
            s0 += (nib & 2u) ? wa.y : 0.f;
            s0 += (nib & 4u) ? wa.z : 0.f;
            s0 += (nib & 8u) ? wa.w : 0.f;
            if (o < 4) {
                float4 wb = *(const float4*)&wo[o + 16][jj * 4];
                s1 += (nib & 1u) ? wb.x : 0.f;
                s1 += (nib & 2u) ? wb.y : 0.f;
                s1 += (nib & 4u) ? wb.z : 0.f;
                s1 += (nib & 8u) ? wb.w : 0.f;
            }
        }
        vo0 = KAPPA * vo0 + s0;
        size_t sidx = ((size_t)slot * 64 + bg * 16 + m) * 160;
        vop[sidx + o * 8 + ns] = vo0;
        if (o < 4) { vo1 = KAPPA * vo1 + s1; vop[sidx + (o + 16) * 8 + ns] = vo1; }
    };

    float in0 = 0, in1 = 0, in2 = 0, in3 = 0;
    if (wv < 4) {
        in0 = __builtin_nontemporal_load(injaddr(0, 0));
        in1 = __builtin_nontemporal_load(injaddr(0, 1));
        in2 = __builtin_nontemporal_load(injaddr(0, 2));
        in3 = __builtin_nontemporal_load(injaddr(0, 3));
    }

    for (int t = t0; t < t1; ++t) {
        float iv0 = in0, iv1 = in1, iv2 = in2, iv3 = in3;

        // ---- P1: own ballots -> LDS; poll partners' z(t-1) ----
        unsigned long long spec = 0; unsigned long long* slot = nullptr;
        if (t > t0) {
            if (wv < 4 && lane < 8) {
                int r = lane >> 1, hf = lane & 1;
                bal32[ns][wv][r][hf] = (unsigned)(bmsel(r) >> (32 * hf));
            }
            if (tid < 224) {
                int pi = tid >> 5; int ns2 = pi + (pi >= ns);
                slot = ex + ((size_t)((bg * 8 + ns2) * 2 + ((t - 1) & 1)) * 32 + (tid & 31));
                spec = atomicAdd(slot, 0ull);       // speculative; checked below
            }
        }
        if (wv < 4 && t + 1 < t1) {                 // inj prefetch (fills poll shadow)
            in0 = __builtin_nontemporal_load(injaddr(t + 1 - t0, 0));
            in1 = __builtin_nontemporal_load(injaddr(t + 1 - t0, 1));
            in2 = __builtin_nontemporal_load(injaddr(t + 1 - t0, 2));
            in3 = __builtin_nontemporal_load(injaddr(t + 1 - t0, 3));
        }
        if (t > t0 && tid < 224) {
            int guard = 0;
            while ((unsigned)(spec >> 32) != (unsigned)(t - 1) && ++guard < 100000)
                spec = atomicAdd(slot, 0ull);
            int sl = tid & 31; int pi = tid >> 5; int ns2 = pi + (pi >= ns);
            bal32[ns2][sl >> 3][(sl >> 1) & 3][sl & 1] = (unsigned)spec;
        }
        barrier_lgkm();

        // ---- P2: build Z fragments in LDS ----
#pragma unroll
        for (int tk = 0; tk < 2; ++tk) {
            int task = tid + tk * 512;              // 0..1023
            int m = task & 15, kl = task >> 4;
            int ks = kl >> 2, lg = kl & 3;
            int bit = ((m >> 2) << 4) + (lg << 2);
            int h = bit >> 5, sh = bit & 31;
            unsigned nib1 = (bal32[ks >> 1][(ks & 1) * 2][m & 3][h] >> sh) & 0xFu;
            unsigned nib2 = (bal32[ks >> 1][(ks & 1) * 2 + 1][m & 3][h] >> sh) & 0xFu;
            uint4 o;
            o.x = ((nib1 & 1u) ? 0x3F80u : 0u) | ((nib1 & 2u) ? 0x3F800000u : 0u);
            o.y = ((nib1 & 4u) ? 0x3F80u : 0u) | ((nib1 & 8u) ? 0x3F800000u : 0u);
            o.z = ((nib2 & 1u) ? 0x3F80u : 0u) | ((nib2 & 2u) ? 0x3F800000u : 0u);
            o.w = ((nib2 & 4u) ? 0x3F80u : 0u) | ((nib2 & 8u) ? 0x3F800000u : 0u);
            zlds[kl * 16 + m] = o;
        }
        barrier_lgkm();

        // ---- P3: GEMM on matrix cores ----
        f32x4 acc = {0.f, 0.f, 0.f, 0.f};
#pragma unroll
        for (int ksl = 0; ksl < 8; ++ksl) {
            int ks = kh * 8 + ksl;
            bf16x8 a = __builtin_bit_cast(bf16x8,
                zlds[(ks * 4 + (lane >> 4)) * 16 + (lane & 15)]);
            acc = __builtin_amdgcn_mfma_f32_16x16x32_bf16(a, wreg[ksl * 3 + 0], acc, 0, 0, 0);
            acc = __builtin_amdgcn_mfma_f32_16x16x32_bf16(a, wreg[ksl * 3 + 1], acc, 0, 0, 0);
            acc = __builtin_amdgcn_mfma_f32_16x16x32_bf16(a, wreg[ksl * 3 + 2], acc, 0, 0, 0);
        }
        if (kh == 1) red[nt][lane] = acc;
        barrier_lgkm();

        // ---- P4: update + ballot + publish || vo partials ----
        if (wv < 4) {
            f32x4 rs = red[wv][lane];
            float vn0 = ALPHA * v0 + (acc[0] + rs[0]) + iv0 - ((zprev & 1) ? THR : 0.f);
            float vn1 = ALPHA * v1 + (acc[1] + rs[1]) + iv1 - ((zprev & 2) ? THR : 0.f);
            float vn2 = ALPHA * v2 + (acc[2] + rs[2]) + iv2 - ((zprev & 4) ? THR : 0.f);
            float vn3 = ALPHA * v3 + (acc[3] + rs[3]) + iv3 - ((zprev & 8) ? THR : 0.f);
            v0 = vn0; v1 = vn1; v2 = vn2; v3 = vn3;
            int z0 = vn0 > THR, z1 = vn1 > THR, z2 = vn2 > THR, z3 = vn3 > THR;
            zprev = z0 | (z1 << 1) | (z2 << 2) | (z3 << 3);
            bm0 = __ballot(z0); bm1 = __ballot(z1); bm2 = __ballot(z2); bm3 = __ballot(z3);
            if (lane < 8) {   // slot index wv*8 + lane  (r=lane>>1, half=lane&1)
                unsigned long long word =
                    ((unsigned long long)(unsigned)t << 32) |
                    (unsigned long long)(unsigned)(bmsel(lane >> 1) >> (32 * (lane & 1)));
                atomicExch(ex + ((size_t)((bg * 8 + ns) * 2 + (t & 1)) * 32 + wv * 8 + lane),
                           word);
            }
        } else if (t > t0) {
            vo_step(t - 1 - t0);    // vo(t-1) from z(t-1) (bal32 own slice)
        }
        barrier_lgkm();
    }

    // ---- tail: vo(t1-1) from z(t1-1); checkpoint state ----
    if (wv < 4 && lane < 8) {
        int r = lane >> 1, hf = lane & 1;
        bal32[ns][wv][r][hf] = (unsigned)(bmsel(r) >> (32 * hf));
    }
    barrier_lgkm();
    if (wv >= 4) {
        vo_step(t1 - 1 - t0);
        int q = tid - 256;
        st_vop[bid * 320 + q] = vo0;
        if (q < 64) st_vop[bid * 320 + 256 + q] = vo1;
    } else {
        f32x4 sv; sv[0] = v0; sv[1] = v1; sv[2] = v2; sv[3] = v3;
        ((f32x4*)st_v)[bid * 256 + tid] = sv;
        if (lane < 4)
            st_bal[bg * 128 + ns * 16 + wv * 4 + lane] = bmsel(lane);
    }
}

// ---------------------------------------------------------------------------
// Kernel R: out_vo[T][b][o] = sum over 8 neuron-slices of the vo partials.
// ---------------------------------------------------------------------------
__global__ void k_vored(const float* __restrict__ vop, float* __restrict__ out_vo,
                        int t0, int t1) {
    int idx = blockIdx.x * 256 + threadIdx.x;
    int n = (t1 - t0) * N_B * N_OUT;
    if (idx >= n) return;
    int s = idx / (N_B * N_OUT);
    int rem = idx - s * (N_B * N_OUT);
    int b = rem / N_OUT, o = rem - b * N_OUT;
    const float* p = vop + ((size_t)s * 64 + b) * 160 + o * 8;
    float acc = p[0] + p[1] + p[2] + p[3] + p[4] + p[5] + p[6] + p[7];
    out_vo[((size_t)(t0 + s) * N_B + b) * N_OUT + o] = acc;   // slot s = vo(t0+s)
}

// ---------------------------------------------------------------------------
// Kernel D: softmax over the 20 outputs; also writes the t=0 rows.
// ---------------------------------------------------------------------------
__global__ void k_softmax(const float* __restrict__ vo_seq,
                          float* __restrict__ out_sm,
                          float* __restrict__ out_vo0)
{
    int idx = blockIdx.x * blockDim.x + threadIdx.x;
    if (idx >= N_B * N_T) return;
    int b = idx / N_T;
    int t = idx - b * N_T;
    float vals[N_OUT];
    if (t == 0) {
#pragma unroll
        for (int o = 0; o < N_OUT; ++o) {
            vals[o] = 0.0f;
            out_vo0[(size_t)b * N_OUT + o] = 0.0f;   // vo[0] = zeros
        }
    } else {
#pragma unroll
        for (int o = 0; o < N_OUT; ++o)
            vals[o] = vo_seq[((size_t)t * N_B + b) * N_OUT + o];
    }
    float mx = vals[0];
#pragma unroll
    for (int o = 1; o < N_OUT; ++o) mx = fmaxf(mx, vals[o]);
    float s = 0.0f;
#pragma unroll
    for (int o = 0; o < N_OUT; ++o) { vals[o] = expf(vals[o] - mx); s += vals[o]; }
    float inv = 1.0f / s;
#pragma unroll
    for (int o = 0; o < N_OUT; ++o)
        out_sm[((size_t)b * N_T + t) * N_OUT + o] = vals[o] * inv;
}

// ---------------------------------------------------------------------------
extern "C" void kernel_launch(void* const* d_in, const int* in_sizes, int n_in,
                              void* d_out, int out_size, void* d_ws, size_t ws_size,
                              hipStream_t stream)
{
    (void)in_sizes; (void)n_in; (void)out_size;
    const float* x     = (const float*)d_in[0];
    const float* w_in  = (const float*)d_in[1];
    const float* w_rec = (const float*)d_in[2];
    const float* w_out = (const float*)d_in[3];
    const float* noise = (const float*)d_in[4];
    const int*   seq   = (const int*)d_in[5];

    float* out    = (float*)d_out;
    float* out_sm = out;                                   // (B,T,20)
    float* out_vo = out + (size_t)N_B * N_T * N_OUT;       // (T,B,20)

    char* ws = (char*)d_ws;
    unsigned* wPack = (unsigned*)ws;
    size_t off = (size_t)98304 * 16;                       // 1.5 MB packed W frags
    off = (off + 255) & ~(size_t)255;
    float* st_v = (float*)(ws + off);                off += (size_t)32 * 256 * 16;
    unsigned long long* st_bal = (unsigned long long*)(ws + off); off += (size_t)4 * 128 * 8;
    float* st_vop = (float*)(ws + off);              off += (size_t)32 * 320 * 4;
    off = (off + 255) & ~(size_t)255;
    unsigned long long* ex = (unsigned long long*)(ws + off);
    off += (size_t)32 * 2 * 32 * 8;                        // 16 KB exchange area
    off = (off + 255) & ~(size_t)255;

    size_t avail = (ws_size > off) ? (ws_size - off) : 0;
    size_t inj_step = (size_t)N_B * N_REC * sizeof(float);       // 128 KB
    size_t vop_step = (size_t)N_B * N_OUT * 8 * sizeof(float);   // 40 KB
    long max_steps = (long)(avail / (inj_step + vop_step));
    int tchunk = (int)((max_steps > (N_T - 1)) ? (N_T - 1) : max_steps);
    if (tchunk < 1) tchunk = 1;
    float* inj = (float*)(ws + off);
    float* vop = (float*)(ws + off + (size_t)tchunk * inj_step);

    k_prep<<<dim3(384), dim3(256), 0, stream>>>(w_rec, wPack, ex);

    for (int t0 = 1; t0 < N_T; t0 += tchunk) {
        int t1 = t0 + tchunk; if (t1 > N_T) t1 = N_T;
        k_inj<<<dim3(512), dim3(512), 0, stream>>>(x, w_in, noise, seq, inj, t0, t1);
        k_scan<<<dim3(32), dim3(512), 0, stream>>>(wPack, inj, w_out, vop,
                                                   t0, t1, st_v, st_bal, st_vop, ex);
        int nred = (t1 - t0) * N_B * N_OUT;
        k_vored<<<dim3((nred + 255) / 256), dim3(256), 0, stream>>>(vop, out_vo, t0, t1);
    }

    k_softmax<<<dim3((N_B * N_T + 255) / 256), dim3(256), 0, stream>>>(out_vo, out_sm, out_vo);
}

// Round 7
// 3771.695 us; speedup vs baseline: 1.0013x; 1.0013x over previous
//
#include <hip/hip_runtime.h>

#define N_B   64
#define N_T   1000
#define N_IN  80
#define N_REC 512
#define N_OUT 20
#define THR 1.0f

constexpr float ALPHA = 0.9512294245007140f; // exp(-1/20)
constexpr float KAPPA = 0.9512294245007140f;

typedef short bf16x8 __attribute__((ext_vector_type(8)));
typedef float f32x4  __attribute__((ext_vector_type(4)));

// lgkm-only barrier: LDS visibility without draining global loads/stores/atomics.
__device__ __forceinline__ void barrier_lgkm() {
    asm volatile("s_waitcnt lgkmcnt(0)" ::: "memory");
    __builtin_amdgcn_s_barrier();
}

__device__ __forceinline__ unsigned short f2bf(float f) {   // RNE fp32->bf16
    unsigned u = __builtin_bit_cast(unsigned, f);
    return (unsigned short)((u + 0x7FFFu + ((u >> 16) & 1u)) >> 16);
}
__device__ __forceinline__ float bf2f(unsigned short h) {
    return __builtin_bit_cast(float, (unsigned)h << 16);
}

// Exchange primitives: stamped words ((t<<32)|mask32) are SELF-VALIDATING, so
// RELAXED order suffices; AGENT scope = coherent across XCDs.
// Poll fast path = atomic LOAD (read-shared, no IC write-port serialization;
// round 5's atomicAdd(p,0) polls caused 327 MB/dispatch of write traffic and
// a 2.4x slowdown). Hardening: after POLL_LOAD_TRIES failed loads, fall back
// to the RMW form whose coherence-point visibility is PROVEN (rounds 3-5) --
// converts a hypothetical stale-load pathology into round-5 behavior instead
// of a guard-storm that looks like a hung container.
#define POLL_LOAD_TRIES 64
__device__ __forceinline__ unsigned long long ex_load(const unsigned long long* p) {
    return __hip_atomic_load(p, __ATOMIC_RELAXED, __HIP_MEMORY_SCOPE_AGENT);
}
__device__ __forceinline__ void ex_store(unsigned long long* p, unsigned long long v) {
    __hip_atomic_store(p, v, __ATOMIC_RELAXED, __HIP_MEMORY_SCOPE_AGENT);
}

// ---------------------------------------------------------------------------
// Kernel P: pack w_rec (diag zeroed) into MFMA B-fragments, 3-way bf16 split
// (hi+mid+lo, residual <= 2^-27 relative -- below fp32 ulp, so the GEMM is
// numerically "another fp32 order"). K-slot mapping kappa(lane,i) =
// 16*(i>>2) + 4*(lane>>4) + (i&3) is applied to BOTH A (spikes, built in
// k_scan) and B (here), so any HW K-permutation cancels exactly.
// Frag addressing: gid = ((((ns*2+kh)*4+nt)*8+ksl)*3+s)*64 + lane.
// Also zeroes the mask-exchange area (stamps must be < t0 at launch; the
// kernel-boundary L2 writeback makes these plain stores visible to k_scan's
// agent-scope atomics -- empirically validated in round 5).
// ---------------------------------------------------------------------------
__global__ void k_prep(const float* __restrict__ w_rec, unsigned* __restrict__ wPack,
                       unsigned long long* __restrict__ ex) {
    int gid = blockIdx.x * 256 + threadIdx.x;     // 0 .. 98303
    if (gid < 32 * 2 * 32) ex[gid] = 0ull;        // 2048 exchange slots
    if (gid >= 8 * 2 * 4 * 8 * 3 * 64) return;
    int lane = gid & 63;
    int fg   = gid >> 6;
    int s    = fg % 3;
    int q    = fg / 3;
    int ksl  = q & 7;
    int nt   = (q >> 3) & 3;
    int kh   = (q >> 5) & 1;
    int ns   = q >> 6;
    int n  = ns * 64 + nt * 16 + (lane & 15);
    int kb = (kh * 8 + ksl) * 32 + 4 * (lane >> 4);
    unsigned u[4];
#pragma unroll
    for (int j = 0; j < 4; ++j) {
        unsigned short h2v[2];
#pragma unroll
        for (int e = 0; e < 2; ++e) {
            int i = j * 2 + e;
            int k = kb + ((i >> 2) << 4) + (i & 3);
            float w0 = (k == n) ? 0.0f : w_rec[(size_t)n * N_REC + k];
            unsigned short h1 = f2bf(w0);
            float r1 = w0 - bf2f(h1);
            unsigned short hm = f2bf(r1);
            float r2 = r1 - bf2f(hm);
            unsigned short hl = f2bf(r2);
            h2v[e] = (s == 0) ? h1 : (s == 1) ? hm : hl;
        }
        u[j] = (unsigned)h2v[0] | ((unsigned)h2v[1] << 16);
    }
    ((uint4*)wPack)[gid] = make_uint4(u[0], u[1], u[2], u[3]);
}

// ---------------------------------------------------------------------------
// Kernel B: inj[(t-t0)*64 + b][r] = dot(x[b,t-1,:], w_in[r,:]) (masked) + noise[t,b,r]
// ---------------------------------------------------------------------------
__global__ __launch_bounds__(512, 2) void k_inj(
    const float* __restrict__ x, const float* __restrict__ w_in,
    const float* __restrict__ noise, const int* __restrict__ seq,
    float* __restrict__ inj, int t0, int t1)
{
    const int r = threadIdx.x;
    float wreg[N_IN];
#pragma unroll
    for (int i = 0; i < N_IN; ++i) wreg[i] = w_in[r * N_IN + i];

    const int P = (t1 - t0) * N_B;
    const int stride = gridDim.x;

    auto nz = [&](int p) -> float {
        int pt = p >> 6, b = p & 63, t = t0 + pt;
        return __builtin_nontemporal_load(noise + ((size_t)t * N_B + b) * N_REC + r);
    };

    int p = blockIdx.x;
    float nxt = (p < P) ? nz(p) : 0.0f;
    for (; p < P; p += stride) {
        float acc = nxt;
        if (p + stride < P) nxt = nz(p + stride);
        int pt = p >> 6;
        int b  = p & 63;
        int t  = t0 + pt;
        if (t - 1 < seq[b]) {
            const float* xr = x + ((size_t)b * N_T + (t - 1)) * N_IN;
#pragma unroll
            for (int i = 0; i < N_IN; ++i) acc = fmaf(wreg[i], xr[i], acc);
        }
        inj[(size_t)p * N_REC + r] = acc;
    }
}

// ---------------------------------------------------------------------------
// Kernel C: sequential scan via dense MFMA. Grid = 32 = 4 batch-groups (bg,
// 16 batches) x 8 neuron-slices (ns, 64 neurons). Per step, per block:
//   P1: write own z(t-1) ballots to LDS; poll the 7 partner slices' stamped
//       ballots (self-validating (t<<32)|mask32 words; relaxed agent atomic
//       loads with RMW fallback; depth-2 parity ring; publish-after-consume
//       causality all-to-all as in rounds 3/4/5).
//   P2: build Z (16x512 bf16 {0,1}) in LDS from the 8 slices' ballots.
//   P3: GEMM acc = Z @ W_slice^T on matrix cores. W in VGPRs (96/wave,
//       loaded once): 8 waves = 4 N-tiles x 2 K-halves, 8 K-steps x 3 splits
//       = 24 mfma_16x16x32_bf16 per wave per step. Zero per-step W traffic.
//   P4: waves 0-3: K-half reduce (LDS), membrane update in C-layout
//       (row=(lane>>4)*4+reg=batch, col=lane&15=neuron), ballot, publish via
//       relaxed agent-scope atomic STORES (fire-and-forget).
//       waves 4-7: vo partial over own 64 neurons from z(t-1) bitmask ->
//       vop buffer (summed into out_vo by k_vored).
// All in-loop barriers are lgkm-only; inj prefetch/publish/vop stores stay
// in flight across them.
// ---------------------------------------------------------------------------
__global__ __launch_bounds__(512, 1) void k_scan(
    const unsigned* __restrict__ wPack, const float* __restrict__ inj,
    const float* __restrict__ w_out, float* __restrict__ vop,
    int t0, int t1,
    float* __restrict__ st_v, unsigned long long* __restrict__ st_bal,
    float* __restrict__ st_vop, unsigned long long* __restrict__ ex)
{
    const int bid  = blockIdx.x;
    const int bg   = bid >> 3;
    const int ns   = bid & 7;
    const int tid  = threadIdx.x;
    const int wv   = tid >> 6;
    const int lane = tid & 63;
    const int nt   = wv & 3;
    const int kh   = wv >> 2;

    __shared__ uint4 zlds[64 * 16];                // [kl=ks*4+lgrp][m], bf16x8 frags
    __shared__ unsigned bal32[8][4][4][2];         // [ns][wave][r][half]
    __shared__ f32x4 red[4][64];                   // K-half partials
    __shared__ alignas(16) float wo[20][68];       // w_out slice, +4 pad (bank-free)

    // W fragments -> VGPRs (once)
    bf16x8 wreg[24];
    {
        const uint4* wp = (const uint4*)wPack + (size_t)(((ns * 2 + kh) * 4 + nt) * 24) * 64;
#pragma unroll
        for (int j = 0; j < 24; ++j)
            wreg[j] = __builtin_bit_cast(bf16x8, wp[j * 64 + lane]);
    }
    for (int idx = tid; idx < 20 * 64; idx += 512)
        wo[idx >> 6][idx & 63] = w_out[(size_t)(idx >> 6) * N_REC + ns * 64 + (idx & 63)];

    float v0 = 0, v1 = 0, v2 = 0, v3 = 0;
    int zprev = 0;
    unsigned long long bm0 = 0, bm1 = 0, bm2 = 0, bm3 = 0;
    float vo0 = 0, vo1 = 0;

    if (t0 == 1) {
        if (tid < 256) (&bal32[0][0][0][0])[tid] = 0u;
    } else {
        if (tid < 256) {
            unsigned long long wd = st_bal[bg * 128 + (tid >> 1)];
            (&bal32[0][0][0][0])[tid] = (unsigned)(wd >> (32 * (tid & 1)));
        }
        if (wv < 4) {
            f32x4 sv = ((const f32x4*)st_v)[bid * 256 + tid];
            v0 = sv[0]; v1 = sv[1]; v2 = sv[2]; v3 = sv[3];
        } else {
            int q = tid - 256;
            vo0 = st_vop[bid * 320 + q];
            if (q < 64) vo1 = st_vop[bid * 320 + 256 + q];
        }
    }
    __syncthreads();
    if (wv < 4) {   // zprev bits from own slice ballots
        int h = lane >> 5, sh = lane & 31;
#pragma unroll
        for (int r = 0; r < 4; ++r)
            zprev |= (int)((bal32[ns][wv][r][h] >> sh) & 1u) << r;
    }

    auto bmsel = [&](int r) -> unsigned long long {
        return (r == 0) ? bm0 : (r == 1) ? bm1 : (r == 2) ? bm2 : bm3;
    };
    auto injaddr = [&](int trel, int r) -> const float* {
        return inj + ((size_t)trel * 64 + bg * 16 + (lane >> 4) * 4 + r) * N_REC
                   + ns * 64 + nt * 16 + (lane & 15);
    };
    // vo partial over own 64 neurons from z bitmask (reads bal32[ns])
    auto vo_step = [&](int slot) {
        int q = tid - 256;
        int m = q & 15, o = q >> 4;
        unsigned long long mask = 0;
#pragma unroll
        for (int w2 = 0; w2 < 4; ++w2) {
            unsigned long long wd = (unsigned long long)bal32[ns][w2][m & 3][0]
                                  | ((unsigned long long)bal32[ns][w2][m & 3][1] << 32);
            mask |= ((wd >> ((m >> 2) * 16)) & 0xFFFFull) << (16 * w2);
        }
        float s0 = 0.f, s1 = 0.f;
#pragma unroll
        for (int jj = 0; jj < 16; ++jj) {
            unsigned nib = (unsigned)(mask >> (4 * jj)) & 0xFu;
            float4 wa = *(const float4*)&wo[o][jj * 4];
            s0 += (nib & 1u) ? wa.x : 0.f;
            s0 += (nib & 2u) ? wa.y : 0.f;
            s0 += (nib & 4u) ? wa.z : 0.f;
            s0 += (nib & 8u) ? wa.w : 0.f;
            if (o < 4) {
                float4 wb = *(const float4*)&wo[o + 16][jj * 4];
                s1 += (nib & 1u) ? wb.x : 0.f;
                s1 += (nib & 2u) ? wb.y : 0.f;
                s1 += (nib & 4u) ? wb.z : 0.f;
                s1 += (nib & 8u) ? wb.w : 0.f;
            }
        }
        vo0 = KAPPA * vo0 + s0;
        size_t sidx = ((size_t)slot * 64 + bg * 16 + m) * 160;
        vop[sidx + o * 8 + ns] = vo0;
        if (o < 4) { vo1 = KAPPA * vo1 + s1; vop[sidx + (o + 16) * 8 + ns] = vo1; }
    };

    float in0 = 0, in1 = 0, in2 = 0, in3 = 0;
    if (wv < 4) {
        in0 = __builtin_nontemporal_load(injaddr(0, 0));
        in1 = __builtin_nontemporal_load(injaddr(0, 1));
        in2 = __builtin_nontemporal_load(injaddr(0, 2));
        in3 = __builtin_nontemporal_load(injaddr(0, 3));
    }

    for (int t = t0; t < t1; ++t) {
        float iv0 = in0, iv1 = in1, iv2 = in2, iv3 = in3;

        // ---- P1: own ballots -> LDS; poll partners' z(t-1) ----
        unsigned long long spec = 0; unsigned long long* slot = nullptr;
        if (t > t0) {
            if (wv < 4 && lane < 8) {
                int r = lane >> 1, hf = lane & 1;
                bal32[ns][wv][r][hf] = (unsigned)(bmsel(r) >> (32 * hf));
            }
            if (tid < 224) {
                int pi = tid >> 5; int ns2 = pi + (pi >= ns);
                slot = ex + ((size_t)((bg * 8 + ns2) * 2 + ((t - 1) & 1)) * 32 + (tid & 31));
                spec = ex_load(slot);               // speculative; checked below
            }
        }
        if (wv < 4 && t + 1 < t1) {                 // inj prefetch (fills poll shadow)
            in0 = __builtin_nontemporal_load(injaddr(t + 1 - t0, 0));
            in1 = __builtin_nontemporal_load(injaddr(t + 1 - t0, 1));
            in2 = __builtin_nontemporal_load(injaddr(t + 1 - t0, 2));
            in3 = __builtin_nontemporal_load(injaddr(t + 1 - t0, 3));
        }
        if (t > t0 && tid < 224) {
            int tries = 0;
            while ((unsigned)(spec >> 32) != (unsigned)(t - 1) && tries < 100000) {
                ++tries;
                spec = (tries < POLL_LOAD_TRIES)
                     ? ex_load(slot)          // fast path: pure read, no IC writes
                     : atomicAdd(slot, 0ull); // proven-coherent RMW fallback
            }
            int sl = tid & 31; int pi = tid >> 5; int ns2 = pi + (pi >= ns);
            bal32[ns2][sl >> 3][(sl >> 1) & 3][sl & 1] = (unsigned)spec;
        }
        barrier_lgkm();

        // ---- P2: build Z fragments in LDS ----
#pragma unroll
        for (int tk = 0; tk < 2; ++tk) {
            int task = tid + tk * 512;              // 0..1023
            int m = task & 15, kl = task >> 4;
            int ks = kl >> 2, lg = kl & 3;
            int bit = ((m >> 2) << 4) + (lg << 2);
            int h = bit >> 5, sh = bit & 31;
            unsigned nib1 = (bal32[ks >> 1][(ks & 1) * 2][m & 3][h] >> sh) & 0xFu;
            unsigned nib2 = (bal32[ks >> 1][(ks & 1) * 2 + 1][m & 3][h] >> sh) & 0xFu;
            uint4 o;
            o.x = ((nib1 & 1u) ? 0x3F80u : 0u) | ((nib1 & 2u) ? 0x3F800000u : 0u);
            o.y = ((nib1 & 4u) ? 0x3F80u : 0u) | ((nib1 & 8u) ? 0x3F800000u : 0u);
            o.z = ((nib2 & 1u) ? 0x3F80u : 0u) | ((nib2 & 2u) ? 0x3F800000u : 0u);
            o.w = ((nib2 & 4u) ? 0x3F80u : 0u) | ((nib2 & 8u) ? 0x3F800000u : 0u);
            zlds[kl * 16 + m] = o;
        }
        barrier_lgkm();

        // ---- P3: GEMM on matrix cores ----
        f32x4 acc = {0.f, 0.f, 0.f, 0.f};
#pragma unroll
        for (int ksl = 0; ksl < 8; ++ksl) {
            int ks = kh * 8 + ksl;
            bf16x8 a = __builtin_bit_cast(bf16x8,
                zlds[(ks * 4 + (lane >> 4)) * 16 + (lane & 15)]);
            acc = __builtin_amdgcn_mfma_f32_16x16x32_bf16(a, wreg[ksl * 3 + 0], acc, 0, 0, 0);
            acc = __builtin_amdgcn_mfma_f32_16x16x32_bf16(a, wreg[ksl * 3 + 1], acc, 0, 0, 0);
            acc = __builtin_amdgcn_mfma_f32_16x16x32_bf16(a, wreg[ksl * 3 + 2], acc, 0, 0, 0);
        }
        if (kh == 1) red[nt][lane] = acc;
        barrier_lgkm();

        // ---- P4: update + ballot + publish || vo partials ----
        if (wv < 4) {
            f32x4 rs = red[wv][lane];
            float vn0 = ALPHA * v0 + (acc[0] + rs[0]) + iv0 - ((zprev & 1) ? THR : 0.f);
            float vn1 = ALPHA * v1 + (acc[1] + rs[1]) + iv1 - ((zprev & 2) ? THR : 0.f);
            float vn2 = ALPHA * v2 + (acc[2] + rs[2]) + iv2 - ((zprev & 4) ? THR : 0.f);
            float vn3 = ALPHA * v3 + (acc[3] + rs[3]) + iv3 - ((zprev & 8) ? THR : 0.f);
            v0 = vn0; v1 = vn1; v2 = vn2; v3 = vn3;
            int z0 = vn0 > THR, z1 = vn1 > THR, z2 = vn2 > THR, z3 = vn3 > THR;
            zprev = z0 | (z1 << 1) | (z2 << 2) | (z3 << 3);
            bm0 = __ballot(z0); bm1 = __ballot(z1); bm2 = __ballot(z2); bm3 = __ballot(z3);
            if (lane < 8) {   // slot index wv*8 + lane  (r=lane>>1, half=lane&1)
                unsigned long long word =
                    ((unsigned long long)(unsigned)t << 32) |
                    (unsigned long long)(unsigned)(bmsel(lane >> 1) >> (32 * (lane & 1)));
                ex_store(ex + ((size_t)((bg * 8 + ns) * 2 + (t & 1)) * 32 + wv * 8 + lane),
                         word);                     // fire-and-forget
            }
        } else if (t > t0) {
            vo_step(t - 1 - t0);    // vo(t-1) from z(t-1) (bal32 own slice)
        }
        barrier_lgkm();
    }

    // ---- tail: vo(t1-1) from z(t1-1); checkpoint state ----
    if (wv < 4 && lane < 8) {
        int r = lane >> 1, hf = lane & 1;
        bal32[ns][wv][r][hf] = (unsigned)(bmsel(r) >> (32 * hf));
    }
    barrier_lgkm();
    if (wv >= 4) {
        vo_step(t1 - 1 - t0);
        int q = tid - 256;
        st_vop[bid * 320 + q] = vo0;
        if (q < 64) st_vop[bid * 320 + 256 + q] = vo1;
    } else {
        f32x4 sv; sv[0] = v0; sv[1] = v1; sv[2] = v2; sv[3] = v3;
        ((f32x4*)st_v)[bid * 256 + tid] = sv;
        if (lane < 4)
            st_bal[bg * 128 + ns * 16 + wv * 4 + lane] = bmsel(lane);
    }
}

// ---------------------------------------------------------------------------
// Kernel R: out_vo[T][b][o] = sum over 8 neuron-slices of the vo partials.
// ---------------------------------------------------------------------------
__global__ void k_vored(const float* __restrict__ vop, float* __restrict__ out_vo,
                        int t0, int t1) {
    int idx = blockIdx.x * 256 + threadIdx.x;
    int n = (t1 - t0) * N_B * N_OUT;
    if (idx >= n) return;
    int s = idx / (N_B * N_OUT);
    int rem = idx - s * (N_B * N_OUT);
    int b = rem / N_OUT, o = rem - b * N_OUT;
    const float* p = vop + ((size_t)s * 64 + b) * 160 + o * 8;
    float acc = p[0] + p[1] + p[2] + p[3] + p[4] + p[5] + p[6] + p[7];
    out_vo[((size_t)(t0 + s) * N_B + b) * N_OUT + o] = acc;   // slot s = vo(t0+s)
}

// ---------------------------------------------------------------------------
// Kernel D: softmax over the 20 outputs; also writes the t=0 rows.
// ---------------------------------------------------------------------------
__global__ void k_softmax(const float* __restrict__ vo_seq,
                          float* __restrict__ out_sm,
                          float* __restrict__ out_vo0)
{
    int idx = blockIdx.x * blockDim.x + threadIdx.x;
    if (idx >= N_B * N_T) return;
    int b = idx / N_T;
    int t = idx - b * N_T;
    float vals[N_OUT];
    if (t == 0) {
#pragma unroll
        for (int o = 0; o < N_OUT; ++o) {
            vals[o] = 0.0f;
            out_vo0[(size_t)b * N_OUT + o] = 0.0f;   // vo[0] = zeros
        }
    } else {
#pragma unroll
        for (int o = 0; o < N_OUT; ++o)
            vals[o] = vo_seq[((size_t)t * N_B + b) * N_OUT + o];
    }
    float mx = vals[0];
#pragma unroll
    for (int o = 1; o < N_OUT; ++o) mx = fmaxf(mx, vals[o]);
    float s = 0.0f;
#pragma unroll
    for (int o = 0; o < N_OUT; ++o) { vals[o] = expf(vals[o] - mx); s += vals[o]; }
    float inv = 1.0f / s;
#pragma unroll
    for (int o = 0; o < N_OUT; ++o)
        out_sm[((size_t)b * N_T + t) * N_OUT + o] = vals[o] * inv;
}

// ---------------------------------------------------------------------------
extern "C" void kernel_launch(void* const* d_in, const int* in_sizes, int n_in,
                              void* d_out, int out_size, void* d_ws, size_t ws_size,
                              hipStream_t stream)
{
    (void)in_sizes; (void)n_in; (void)out_size;
    const float* x     = (const float*)d_in[0];
    const float* w_in  = (const float*)d_in[1];
    const float* w_rec = (const float*)d_in[2];
    const float* w_out = (const float*)d_in[3];
    const float* noise = (const float*)d_in[4];
    const int*   seq   = (const int*)d_in[5];

    float* out    = (float*)d_out;
    float* out_sm = out;                                   // (B,T,20)
    float* out_vo = out + (size_t)N_B * N_T * N_OUT;       // (T,B,20)

    char* ws = (char*)d_ws;
    unsigned* wPack = (unsigned*)ws;
    size_t off = (size_t)98304 * 16;                       // 1.5 MB packed W frags
    off = (off + 255) & ~(size_t)255;
    float* st_v = (float*)(ws + off);                off += (size_t)32 * 256 * 16;
    unsigned long long* st_bal = (unsigned long long*)(ws + off); off += (size_t)4 * 128 * 8;
    float* st_vop = (float*)(ws + off);              off += (size_t)32 * 320 * 4;
    off = (off + 255) & ~(size_t)255;
    unsigned long long* ex = (unsigned long long*)(ws + off);
    off += (size_t)32 * 2 * 32 * 8;                        // 16 KB exchange area
    off = (off + 255) & ~(size_t)255;

    size_t avail = (ws_size > off) ? (ws_size - off) : 0;
    size_t inj_step = (size_t)N_B * N_REC * sizeof(float);       // 128 KB
    size_t vop_step = (size_t)N_B * N_OUT * 8 * sizeof(float);   // 40 KB
    long max_steps = (long)(avail / (inj_step + vop_step));
    int tchunk = (int)((max_steps > (N_T - 1)) ? (N_T - 1) : max_steps);
    if (tchunk < 1) tchunk = 1;
    float* inj = (float*)(ws + off);
    float* vop = (float*)(ws + off + (size_t)tchunk * inj_step);

    k_prep<<<dim3(384), dim3(256), 0, stream>>>(w_rec, wPack, ex);

    for (int t0 = 1; t0 < N_T; t0 += tchunk) {
        int t1 = t0 + tchunk; if (t1 > N_T) t1 = N_T;
        k_inj<<<dim3(512), dim3(512), 0, stream>>>(x, w_in, noise, seq, inj, t0, t1);
        k_scan<<<dim3(32), dim3(512), 0, stream>>>(wPack, inj, w_out, vop,
                                                   t0, t1, st_v, st_bal, st_vop, ex);
        int nred = (t1 - t0) * N_B * N_OUT;
        k_vored<<<dim3((nred + 255) / 256), dim3(256), 0, stream>>>(vop, out_vo, t0, t1);
    }

    k_softmax<<<dim3((N_B * N_T + 255) / 256), dim3(256), 0, stream>>>(out_vo, out_sm, out_vo);
}